// Round 2
// baseline (868.712 us; speedup 1.0000x reference)
//
#include <hip/hip_runtime.h>
#include <hip/hip_bf16.h>
#include <hip/hip_fp16.h>

// Problem constants (TempoAttention: N=8, T=1024, D=128, H=8)
#define NB 8
#define TT 1024
#define DD 128
#define HH 8

using short8  = __attribute__((ext_vector_type(8))) short;    // 8 bf16 (4 VGPRs)
using floatx4 = __attribute__((ext_vector_type(4))) float;    // MFMA C/D
using half8   = __attribute__((ext_vector_type(8))) _Float16;
using half4   = __attribute__((ext_vector_type(4))) _Float16; // packed b64 LDS store
using intx4   = __attribute__((ext_vector_type(4))) int;

// fp32 -> bf16 (RNE)
__device__ __forceinline__ unsigned short f2bf_u(float f) {
    union { float f; unsigned u; } v; v.f = f;
    return (unsigned short)((v.u + 0x7fffu + ((v.u >> 16) & 1u)) >> 16);
}

// ---------------------------------------------------------------------------
// Projection kernel: q = x@Wq^T+bq etc. -> bf16 in MFMA-friendly layouts.
//   q,k : [n,h,t,d]  (row = token, contiguous d)
//   v   : [n,h,d,t]  (transposed so PV B-fragments are contiguous along t)
// GEMM M=8192 (n,t), N=1024 (h*d), K=128. block = 4 waves x 16 rows, 128 cols.
// VERIFIED (outputs 0/1 passed R1) — do not touch.
// ---------------------------------------------------------------------------
__global__ __launch_bounds__(256, 2) void proj_kernel(
    const float* __restrict__ x,
    const float* __restrict__ Wq, const float* __restrict__ bq,
    const float* __restrict__ Wk, const float* __restrict__ bk,
    const float* __restrict__ Wv, const float* __restrict__ bv,
    unsigned short* __restrict__ qb, unsigned short* __restrict__ kb,
    unsigned short* __restrict__ vt)
{
    int b     = blockIdx.x;
    int which = b >> 10;          // 0=q 1=k 2=v
    int rem   = b & 1023;
    int mblk  = rem >> 3;         // 0..127 (64 rows each)
    int nblk  = rem & 7;          // 0..7   (128 cols each)
    int tid   = threadIdx.x;
    int wid   = tid >> 6, lane = tid & 63;
    int l15   = lane & 15, quad = lane >> 4;
    int m0    = mblk * 64 + wid * 16;

    const float* W    = (which == 0) ? Wq : (which == 1) ? Wk : Wv;
    const float* bias = (which == 0) ? bq : (which == 1) ? bk : bv;
    unsigned short* dst = (which == 0) ? qb : (which == 1) ? kb : vt;

    // A fragments: x rows (fp32 -> bf16), A[m=l15][k=quad*8+j]
    short8 a[4];
    const float* xr = x + (size_t)(m0 + l15) * DD + quad * 8;
    #pragma unroll
    for (int kk = 0; kk < 4; ++kk) {
        const float* p = xr + kk * 32;
        short8 t;
        #pragma unroll
        for (int j = 0; j < 8; ++j) t[j] = (short)f2bf_u(p[j]);
        a[kk] = t;
    }

    floatx4 acc[8];
    #pragma unroll
    for (int ct = 0; ct < 8; ++ct) acc[ct] = (floatx4){0.f, 0.f, 0.f, 0.f};

    for (int ct = 0; ct < 8; ++ct) {
        int c = nblk * 128 + ct * 16 + l15;          // output channel (B n-index)
        const float* wr = W + (size_t)c * DD + quad * 8;
        #pragma unroll
        for (int kk = 0; kk < 4; ++kk) {
            const float* p = wr + kk * 32;
            short8 bf;
            #pragma unroll
            for (int j = 0; j < 8; ++j) bf[j] = (short)f2bf_u(p[j]);
            acc[ct] = __builtin_amdgcn_mfma_f32_16x16x32_bf16(a[kk], bf, acc[ct], 0, 0, 0);
        }
    }

    // Epilogue: C/D layout col=l15, row=quad*4+r
    #pragma unroll
    for (int ct = 0; ct < 8; ++ct) {
        int c  = nblk * 128 + ct * 16 + l15;
        int h  = c >> 7, dd = c & 127;
        float bsv = bias[c];
        #pragma unroll
        for (int r = 0; r < 4; ++r) {
            int m = m0 + quad * 4 + r;
            int n = m >> 10, t = m & 1023;
            unsigned short v = f2bf_u(acc[ct][r] + bsv);
            size_t idx;
            if (which == 2) idx = ((size_t)(n * HH + h) * DD + dd) * TT + t;   // v^T
            else            idx = ((size_t)(n * HH + h) * TT + t) * DD + dd;   // q,k
            dst[idx] = v;
        }
    }
}

// ---------------------------------------------------------------------------
// Fused attention kernel. One block = (n,h) x 16 query rows. 256 threads.
// R3 theory: R1/R2 were latency-starved at 2 waves/SIMD (66 KB LDS -> 2
// blocks/CU, Occupancy 20%). Halving the Q-tile to 16 rows cuts LDS to 33 KB
// -> 4 blocks/CU -> 4 waves/SIMD, doubling latency hiding on the wts HBM
// stream. Also: wts ring-pipeline deepened to 4 (fully unrolled, static
// indices), phase-3 V/P prefetch depth 2, NT stores reverted (R1 showed NT
// inflates partial-line writes: WRITE_SIZE 302->365 MB).
// Math identical to verified R1: same MFMA sequence (swapped QK^T), same
// -65504 sentinel, same fp16/bf16 path.
// ---------------------------------------------------------------------------
#define SSTRIDE 1032  // halves; +8 pad breaks power-of-2 bank aliasing
#define QROWS 16

__global__ __launch_bounds__(256, 4) void attn_kernel(
    const unsigned short* __restrict__ qb, const unsigned short* __restrict__ kb,
    const unsigned short* __restrict__ vt,
    const float* __restrict__ wts, const int* __restrict__ mask,
    float* __restrict__ out, float* __restrict__ outagg, float* __restrict__ att)
{
    extern __shared__ char smem[];
    _Float16* S   = (_Float16*)smem;
    float* rowinv = (float*)(smem + QROWS * SSTRIDE * 2);

    // XCD swizzle: all 64 tiles of one (n,h) group land on one XCD (b%8)
    int b    = blockIdx.x;
    int slot = b & 7, j = b >> 3;
    int tile = j & 63, gq = j >> 6;
    int g    = gq * 8 + slot;          // n*H + h, 0..63
    int n    = g >> 3, h = g & 7;
    int t0   = tile * QROWS;

    int tid = threadIdx.x;
    int wid = tid >> 6, lane = tid & 63;
    int l15 = lane & 15, quad = lane >> 4;

    const unsigned short* qp = qb + ((size_t)g * TT + t0) * DD;
    const unsigned short* kp = kb + (size_t)g * TT * DD;
    const unsigned short* vp = vt + (size_t)g * DD * TT;
    const float* wp = wts + (size_t)g * TT * TT + (size_t)t0 * TT;
    const int*   mp = mask + n * TT;
    float* attp = att + (size_t)g * TT * TT + (size_t)t0 * TT;

    // ---- Phase 1: S = mask(weights * scale * (Q K^T)) ----
    // Swapped MFMA (verified R1): mfma(K,Q) -> D col=l15=query, row=quad*4+r=key,
    // so per-lane w/mask are 4 CONSECUTIVE keys -> float4/int4 loads.
    short8 aq[4];
    #pragma unroll
    for (int kk = 0; kk < 4; ++kk)
        aq[kk] = *(const short8*)(qp + (size_t)l15 * DD + kk * 32 + quad * 8);

    const int c0 = wid * 256;                 // each wave owns a 256-key strip
    const float scale = 0.08838834764831845f; // 1/sqrt(128)

    const float* wrow = wp + (size_t)l15 * TT + c0 + quad * 4;   // w[query=l15][key..]
    const unsigned short* kcol = kp + (size_t)(c0 + l15) * DD + quad * 8;
    const int* mrow = mp + c0 + quad * 4;
    _Float16* sst = S + (size_t)l15 * SSTRIDE + c0 + quad * 4;

    // 4-deep ring pipeline on the wts/mask HBM stream; 1-deep on K (L2).
    // Loop fully unrolled so all ring indices are compile-time (no scratch).
    floatx4 wbuf[4]; intx4 mbuf[4];
    #pragma unroll
    for (int p = 0; p < 4; ++p) {
        wbuf[p] = *(const floatx4*)(wrow + p * 16);
        mbuf[p] = *(const intx4*)(mrow + p * 16);
    }
    short8 kf[4];
    #pragma unroll
    for (int kk = 0; kk < 4; ++kk) kf[kk] = *(const short8*)(kcol + kk * 32);

    #pragma unroll
    for (int ct = 0; ct < 16; ++ct) {
        // K prefetch (tile ct+1, clamped) issued first.
        const int ctk = (ct + 1 < 16) ? ct + 1 : 15;
        short8 kn[4];
        #pragma unroll
        for (int kk = 0; kk < 4; ++kk)
            kn[kk] = *(const short8*)(kcol + ctk * 16 * DD + kk * 32);
        // wts/mask prefetch 4 tiles ahead (compile-time guard — unrolled).
        floatx4 nw; intx4 nmk;
        if (ct + 4 < 16) {
            nw  = *(const floatx4*)(wrow + (ct + 4) * 16);
            nmk = *(const intx4*)(mrow + (ct + 4) * 16);
        }

        floatx4 acc = {0.f, 0.f, 0.f, 0.f};
        #pragma unroll
        for (int kk = 0; kk < 4; ++kk)
            acc = __builtin_amdgcn_mfma_f32_16x16x32_bf16(kf[kk], aq[kk], acc, 0, 0, 0);

        floatx4 w = wbuf[ct & 3]; intx4 mk = mbuf[ct & 3];
        half4 hh;
        #pragma unroll
        for (int r = 0; r < 4; ++r)
            hh[r] = (_Float16)(mk[r] ? -65504.f : acc[r] * scale * w[r]);
        *(half4*)(sst + ct * 16) = hh;

        #pragma unroll
        for (int kk = 0; kk < 4; ++kk) kf[kk] = kn[kk];
        if (ct + 4 < 16) { wbuf[ct & 3] = nw; mbuf[ct & 3] = nmk; }
    }
    __syncthreads();

    // ---- Phase 2: softmax. 16 lanes per row -> shfl_xor(1,2,4,8) reductions.
    // Score row cached in regs (single LDS pass), 8-way ILP chains.
    int row = tid >> 4;          // 0..15
    int jj  = tid & 15;          // 0..15, owns cols {jj*8 + i*128 + e}
    _Float16* Srow = S + row * SSTRIDE + jj * 8;

    half8 hv[8];
    #pragma unroll
    for (int i = 0; i < 8; ++i) hv[i] = *(const half8*)(Srow + i * 128);

    float m8[8];
    #pragma unroll
    for (int e = 0; e < 8; ++e) m8[e] = (float)hv[0][e];
    #pragma unroll
    for (int i = 1; i < 8; ++i)
        #pragma unroll
        for (int e = 0; e < 8; ++e) m8[e] = fmaxf(m8[e], (float)hv[i][e]);
    float mx = fmaxf(fmaxf(fmaxf(m8[0], m8[1]), fmaxf(m8[2], m8[3])),
                     fmaxf(fmaxf(m8[4], m8[5]), fmaxf(m8[6], m8[7])));
    mx = fmaxf(mx, __shfl_xor(mx, 1));
    mx = fmaxf(mx, __shfl_xor(mx, 2));
    mx = fmaxf(mx, __shfl_xor(mx, 4));
    mx = fmaxf(mx, __shfl_xor(mx, 8));

    float s8[8] = {0.f,0.f,0.f,0.f,0.f,0.f,0.f,0.f};
    #pragma unroll
    for (int i = 0; i < 8; ++i)
        #pragma unroll
        for (int e = 0; e < 8; ++e) s8[e] += __expf((float)hv[i][e] - mx);
    float sum = ((s8[0] + s8[1]) + (s8[2] + s8[3])) + ((s8[4] + s8[5]) + (s8[6] + s8[7]));
    sum += __shfl_xor(sum, 1);
    sum += __shfl_xor(sum, 2);
    sum += __shfl_xor(sum, 4);
    sum += __shfl_xor(sum, 8);
    float iv = 1.f / sum;
    if (jj == 0) rowinv[row] = iv;

    float* arow = attp + (size_t)row * TT + jj * 8;
    #pragma unroll
    for (int i = 0; i < 8; ++i) {
        half8 ev;
        floatx4 o0, o1;
        #pragma unroll
        for (int e = 0; e < 8; ++e) {
            float ex = __expf((float)hv[i][e] - mx);
            ev[e] = __builtin_bit_cast(_Float16, f2bf_u(ex));  // bf16 bits for PV
            float a = ex * iv;                                  // full-precision att
            if (e < 4) o0[e] = a; else o1[e - 4] = a;
        }
        *(half8*)(Srow + i * 128) = ev;
        *(floatx4*)(arow + i * 128)     = o0;   // plain stores: L2 merges lines
        *(floatx4*)(arow + i * 128 + 4) = o1;
    }
    __syncthreads();   // e-bits + rowinv visible to all before PV

    // ---- Phase 3: out = (e @ V) * inv_l. Each wave owns 32 of 128 d-cols ----
    // A-frag rows = 16 queries (l15). 2-deep prefetch on V (L2) and P (LDS).
    int c0p = wid * 32;
    const unsigned short* vrow0 = vp + (size_t)(c0p + l15) * TT + quad * 8;
    const unsigned short* vrow1 = vp + (size_t)(c0p + 16 + l15) * TT + quad * 8;
    const _Float16* sp = S + (size_t)l15 * SSTRIDE + quad * 8;

    floatx4 o0 = {0.f,0.f,0.f,0.f}, o1 = o0;
    short8 vb0[2], vb1[2], pa[2];
    #pragma unroll
    for (int p = 0; p < 2; ++p) {
        vb0[p] = *(const short8*)(vrow0 + p * 32);
        vb1[p] = *(const short8*)(vrow1 + p * 32);
        pa[p]  = __builtin_bit_cast(short8, *(const half8*)(sp + p * 32));
    }
    #pragma unroll
    for (int ks = 0; ks < 32; ++ks) {
        const int sl = ks & 1;
        short8 a = pa[sl], b0 = vb0[sl], b1 = vb1[sl];
        if (ks + 2 < 32) {
            vb0[sl] = *(const short8*)(vrow0 + (ks + 2) * 32);
            vb1[sl] = *(const short8*)(vrow1 + (ks + 2) * 32);
            pa[sl]  = __builtin_bit_cast(short8, *(const half8*)(sp + (ks + 2) * 32));
        }
        o0 = __builtin_amdgcn_mfma_f32_16x16x32_bf16(a, b0, o0, 0, 0, 0);
        o1 = __builtin_amdgcn_mfma_f32_16x16x32_bf16(a, b1, o1, 0, 0, 0);
    }

    #pragma unroll
    for (int ct = 0; ct < 2; ++ct) {
        int col = c0p + ct * 16 + l15;     // d index 0..127
        floatx4 oo = (ct == 0) ? o0 : o1;
        float agg = 0.f;
        #pragma unroll
        for (int r = 0; r < 4; ++r) {
            int rw = quad * 4 + r;         // query row 0..15
            float val = oo[r] * rowinv[rw];
            out[((size_t)(n * TT + t0 + rw)) * (HH * DD) + h * DD + col] = val;
            agg += val;
        }
        atomicAdd(outagg + n * (HH * DD) + h * DD + col, agg * (1.f / (float)TT));
    }
}

extern "C" void kernel_launch(void* const* d_in, const int* in_sizes, int n_in,
                              void* d_out, int out_size, void* d_ws, size_t ws_size,
                              hipStream_t stream) {
    const float* x    = (const float*)d_in[0];
    const int*   mask = (const int*)d_in[1];      // bool -> int32 (verified R1)
    const float* wts  = (const float*)d_in[2];
    const float* Wq = (const float*)d_in[3];
    const float* bq = (const float*)d_in[4];
    const float* Wk = (const float*)d_in[5];
    const float* bk = (const float*)d_in[6];
    const float* Wv = (const float*)d_in[7];
    const float* bv = (const float*)d_in[8];

    float* out    = (float*)d_out;                                  // [8,1024,1024]
    float* outagg = out + (size_t)NB * TT * HH * DD;                // [8,1024]
    float* att    = outagg + NB * HH * DD;                          // [8,8,1024,1024]

    unsigned short* qb = (unsigned short*)d_ws;                     // 16.78 MB each
    unsigned short* kb = qb + (size_t)NB * HH * TT * DD;
    unsigned short* vt = kb + (size_t)NB * HH * TT * DD;

    hipMemsetAsync(outagg, 0, (size_t)NB * HH * DD * sizeof(float), stream);
    proj_kernel<<<3072, 256, 0, stream>>>(x, Wq, bq, Wk, bk, Wv, bv, qb, kb, vt);
    attn_kernel<<<4096, 256, QROWS * SSTRIDE * 2 + 64, stream>>>(
        qb, kb, vt, wts, mask, out, outagg, att);
}

// Round 3
// 788.097 us; speedup vs baseline: 1.1023x; 1.1023x over previous
//
#include <hip/hip_runtime.h>
#include <hip/hip_bf16.h>
#include <hip/hip_fp16.h>

// Problem constants (TempoAttention: N=8, T=1024, D=128, H=8)
#define NB 8
#define TT 1024
#define DD 128
#define HH 8

using short8  = __attribute__((ext_vector_type(8))) short;    // 8 bf16 (4 VGPRs)
using floatx4 = __attribute__((ext_vector_type(4))) float;    // MFMA C/D
using half8   = __attribute__((ext_vector_type(8))) _Float16;
using half4   = __attribute__((ext_vector_type(4))) _Float16; // packed b64 LDS store
using intx4   = __attribute__((ext_vector_type(4))) int;

// fp32 -> bf16 (RNE)
__device__ __forceinline__ unsigned short f2bf_u(float f) {
    union { float f; unsigned u; } v; v.f = f;
    return (unsigned short)((v.u + 0x7fffu + ((v.u >> 16) & 1u)) >> 16);
}

// ---------------------------------------------------------------------------
// Projection kernel: q = x@Wq^T+bq etc. -> bf16 in MFMA-friendly layouts.
//   q,k : [n,h,t,d]  (row = token, contiguous d)
//   v   : [n,h,d,t]  (transposed so PV B-fragments are contiguous along t)
// GEMM M=8192 (n,t), N=1024 (h*d), K=128. block = 4 waves x 16 rows, 128 cols.
// VERIFIED — do not touch.
// ---------------------------------------------------------------------------
__global__ __launch_bounds__(256, 2) void proj_kernel(
    const float* __restrict__ x,
    const float* __restrict__ Wq, const float* __restrict__ bq,
    const float* __restrict__ Wk, const float* __restrict__ bk,
    const float* __restrict__ Wv, const float* __restrict__ bv,
    unsigned short* __restrict__ qb, unsigned short* __restrict__ kb,
    unsigned short* __restrict__ vt)
{
    int b     = blockIdx.x;
    int which = b >> 10;          // 0=q 1=k 2=v
    int rem   = b & 1023;
    int mblk  = rem >> 3;         // 0..127 (64 rows each)
    int nblk  = rem & 7;          // 0..7   (128 cols each)
    int tid   = threadIdx.x;
    int wid   = tid >> 6, lane = tid & 63;
    int l15   = lane & 15, quad = lane >> 4;
    int m0    = mblk * 64 + wid * 16;

    const float* W    = (which == 0) ? Wq : (which == 1) ? Wk : Wv;
    const float* bias = (which == 0) ? bq : (which == 1) ? bk : bv;
    unsigned short* dst = (which == 0) ? qb : (which == 1) ? kb : vt;

    // A fragments: x rows (fp32 -> bf16), A[m=l15][k=quad*8+j]
    short8 a[4];
    const float* xr = x + (size_t)(m0 + l15) * DD + quad * 8;
    #pragma unroll
    for (int kk = 0; kk < 4; ++kk) {
        const float* p = xr + kk * 32;
        short8 t;
        #pragma unroll
        for (int j = 0; j < 8; ++j) t[j] = (short)f2bf_u(p[j]);
        a[kk] = t;
    }

    floatx4 acc[8];
    #pragma unroll
    for (int ct = 0; ct < 8; ++ct) acc[ct] = (floatx4){0.f, 0.f, 0.f, 0.f};

    for (int ct = 0; ct < 8; ++ct) {
        int c = nblk * 128 + ct * 16 + l15;          // output channel (B n-index)
        const float* wr = W + (size_t)c * DD + quad * 8;
        #pragma unroll
        for (int kk = 0; kk < 4; ++kk) {
            const float* p = wr + kk * 32;
            short8 bf;
            #pragma unroll
            for (int j = 0; j < 8; ++j) bf[j] = (short)f2bf_u(p[j]);
            acc[ct] = __builtin_amdgcn_mfma_f32_16x16x32_bf16(a[kk], bf, acc[ct], 0, 0, 0);
        }
    }

    // Epilogue: C/D layout col=l15, row=quad*4+r
    #pragma unroll
    for (int ct = 0; ct < 8; ++ct) {
        int c  = nblk * 128 + ct * 16 + l15;
        int h  = c >> 7, dd = c & 127;
        float bsv = bias[c];
        #pragma unroll
        for (int r = 0; r < 4; ++r) {
            int m = m0 + quad * 4 + r;
            int n = m >> 10, t = m & 1023;
            unsigned short v = f2bf_u(acc[ct][r] + bsv);
            size_t idx;
            if (which == 2) idx = ((size_t)(n * HH + h) * DD + dd) * TT + t;   // v^T
            else            idx = ((size_t)(n * HH + h) * TT + t) * DD + dd;   // q,k
            dst[idx] = v;
        }
    }
}

// ---------------------------------------------------------------------------
// Fused attention kernel. One block = (n,h) x 32 query rows. 256 threads.
//
// R3: restore the 32-row R1 structure (R2 proved per-wave ILP > occupancy:
// halving the tile doubled occupancy 20->42% but cost 43% time). Single new
// lever: TRUE pipeline depth. 4-slot ring buffers, prefetch distance 3, on
// every latency-bound stream (K+wts+mask in phase 1, V+P in phase 3; V ring
// pre-filled during phase 2). Previously the rotate pattern waited on its own
// prefetch each iteration (effective depth 1), exposing ~450cy of L3 latency
// per iteration — K/V get flushed from L2 by the 8MB/group wts+att streams,
// so their reads are L3-latency, not L2.
// All ring indices compile-time (full unroll) to avoid scratch.
// Math identical to verified R1: swapped QK^T mfma(K,Q), -65504 sentinel,
// same fp16/bf16 path. Plain stores (R1 NT inflated WRITE_SIZE 302->365MB).
// ---------------------------------------------------------------------------
#define SSTRIDE 1032  // halves; +8 pad breaks power-of-2 bank aliasing

__global__ __launch_bounds__(256, 2) void attn_kernel(
    const unsigned short* __restrict__ qb, const unsigned short* __restrict__ kb,
    const unsigned short* __restrict__ vt,
    const float* __restrict__ wts, const int* __restrict__ mask,
    float* __restrict__ out, float* __restrict__ outagg, float* __restrict__ att)
{
    extern __shared__ char smem[];
    _Float16* S   = (_Float16*)smem;
    float* rowinv = (float*)(smem + 32 * SSTRIDE * 2);

    // XCD swizzle: all 32 tiles of one (n,h) group land on one XCD (b%8)
    int b    = blockIdx.x;
    int slot = b & 7, j = b >> 3;
    int tile = j & 31, gq = j >> 5;
    int g    = gq * 8 + slot;          // n*H + h, 0..63
    int n    = g >> 3, h = g & 7;
    int t0   = tile * 32;

    int tid = threadIdx.x;
    int wid = tid >> 6, lane = tid & 63;
    int l15 = lane & 15, quad = lane >> 4;

    const unsigned short* qp = qb + ((size_t)g * TT + t0) * DD;
    const unsigned short* kp = kb + (size_t)g * TT * DD;
    const unsigned short* vp = vt + (size_t)g * DD * TT;
    const float* wp = wts + (size_t)g * TT * TT + (size_t)t0 * TT;
    const int*   mp = mask + n * TT;
    float* attp = att + (size_t)g * TT * TT + (size_t)t0 * TT;

    // ---- Phase 1: S = mask(weights * scale * (Q K^T)) ----
    // Swapped MFMA (verified): mfma(K,Q) -> D col=l15=query, row=quad*4+r=key,
    // so per-lane w/mask are 4 CONSECUTIVE keys -> float4/int4 loads.
    short8 aq[2][4];
    #pragma unroll
    for (int rt = 0; rt < 2; ++rt)
        #pragma unroll
        for (int kk = 0; kk < 4; ++kk)
            aq[rt][kk] = *(const short8*)(qp + (size_t)(rt * 16 + l15) * DD + kk * 32 + quad * 8);

    const int c0 = wid * 256;                 // each wave owns a 256-key strip
    const float scale = 0.08838834764831845f; // 1/sqrt(128)

    const float* wrow0 = wp + (size_t)l15 * TT + c0 + quad * 4;  // w[query=l15][key..]
    const float* wrow1 = wrow0 + (size_t)16 * TT;                // queries +16
    const unsigned short* kcol = kp + (size_t)(c0 + l15) * DD + quad * 8;
    const int* mrow = mp + c0 + quad * 4;
    _Float16* sst0 = S + (size_t)l15 * SSTRIDE + c0 + quad * 4;
    _Float16* sst1 = sst0 + (size_t)16 * SSTRIDE;

    // 4-slot rings, prefetch distance 3, all indices static (full unroll).
    short8  kring[4][4];    // [slot][kk]
    floatx4 wring[4][2];    // [slot][query-half]
    intx4   mring[4];       // [slot]

    #pragma unroll
    for (int p = 0; p < 3; ++p) {
        #pragma unroll
        for (int kk = 0; kk < 4; ++kk)
            kring[p][kk] = *(const short8*)(kcol + p * 16 * DD + kk * 32);
        wring[p][0] = *(const floatx4*)(wrow0 + p * 16);
        wring[p][1] = *(const floatx4*)(wrow1 + p * 16);
        mring[p]    = *(const intx4*)(mrow + p * 16);
    }

    #pragma unroll
    for (int ct = 0; ct < 16; ++ct) {
        if (ct + 3 < 16) {                   // compile-time guard (unrolled)
            const int pf = ct + 3, sp = pf & 3;
            #pragma unroll
            for (int kk = 0; kk < 4; ++kk)
                kring[sp][kk] = *(const short8*)(kcol + pf * 16 * DD + kk * 32);
            wring[sp][0] = *(const floatx4*)(wrow0 + pf * 16);
            wring[sp][1] = *(const floatx4*)(wrow1 + pf * 16);
            mring[sp]    = *(const intx4*)(mrow + pf * 16);
        }
        const int sl = ct & 3;

        floatx4 acc0 = {0.f,0.f,0.f,0.f}, acc1 = {0.f,0.f,0.f,0.f};
        #pragma unroll
        for (int kk = 0; kk < 4; ++kk) {
            acc0 = __builtin_amdgcn_mfma_f32_16x16x32_bf16(kring[sl][kk], aq[0][kk], acc0, 0, 0, 0);
            acc1 = __builtin_amdgcn_mfma_f32_16x16x32_bf16(kring[sl][kk], aq[1][kk], acc1, 0, 0, 0);
        }

        floatx4 w0 = wring[sl][0], w1 = wring[sl][1];
        intx4 mk = mring[sl];
        half4 h0, h1;
        #pragma unroll
        for (int r = 0; r < 4; ++r) {
            h0[r] = (_Float16)(mk[r] ? -65504.f : acc0[r] * scale * w0[r]);
            h1[r] = (_Float16)(mk[r] ? -65504.f : acc1[r] * scale * w1[r]);
        }
        *(half4*)(sst0 + ct * 16) = h0;
        *(half4*)(sst1 + ct * 16) = h1;
    }
    __syncthreads();

    // ---- Phase 2: softmax. 8 lanes per row (same wave) -> shfl reductions.
    // Score row cached in regs (single LDS pass), 8-way ILP chains.
    int row = tid >> 3;          // 0..31
    int jj  = tid & 7;           // 0..7, owns cols {jj*8 + i*64 + e}
    _Float16* Srow = S + row * SSTRIDE + jj * 8;

    half8 hv[16];
    #pragma unroll
    for (int i = 0; i < 16; ++i) hv[i] = *(const half8*)(Srow + i * 64);

    float m8[8];
    #pragma unroll
    for (int e = 0; e < 8; ++e) m8[e] = (float)hv[0][e];
    #pragma unroll
    for (int i = 1; i < 16; ++i)
        #pragma unroll
        for (int e = 0; e < 8; ++e) m8[e] = fmaxf(m8[e], (float)hv[i][e]);
    float mx = fmaxf(fmaxf(fmaxf(m8[0], m8[1]), fmaxf(m8[2], m8[3])),
                     fmaxf(fmaxf(m8[4], m8[5]), fmaxf(m8[6], m8[7])));
    mx = fmaxf(mx, __shfl_xor(mx, 1));
    mx = fmaxf(mx, __shfl_xor(mx, 2));
    mx = fmaxf(mx, __shfl_xor(mx, 4));

    float s8[8] = {0.f,0.f,0.f,0.f,0.f,0.f,0.f,0.f};
    #pragma unroll
    for (int i = 0; i < 16; ++i)
        #pragma unroll
        for (int e = 0; e < 8; ++e) s8[e] += __expf((float)hv[i][e] - mx);
    float sum = ((s8[0] + s8[1]) + (s8[2] + s8[3])) + ((s8[4] + s8[5]) + (s8[6] + s8[7]));
    sum += __shfl_xor(sum, 1);
    sum += __shfl_xor(sum, 2);
    sum += __shfl_xor(sum, 4);
    float iv = 1.f / sum;              // all 8 lanes of the row group have it
    if (jj == 0) rowinv[row] = iv;     // PV epilogue needs it per C-row

    // Pre-fill phase-3 V ring NOW (independent of S) — its HBM/L3 latency
    // hides under the exp/store loop below.
    int c0p = wid * 32;
    const unsigned short* vrow0 = vp + (size_t)(c0p + l15) * TT + quad * 8;
    const unsigned short* vrow1 = vp + (size_t)(c0p + 16 + l15) * TT + quad * 8;
    short8 vr0[4], vr1[4];
    #pragma unroll
    for (int p = 0; p < 3; ++p) {
        vr0[p] = *(const short8*)(vrow0 + p * 32);
        vr1[p] = *(const short8*)(vrow1 + p * 32);
    }

    float* arow = attp + (size_t)row * TT + jj * 8;
    #pragma unroll
    for (int i = 0; i < 16; ++i) {
        half8 ev;
        floatx4 o0, o1;
        #pragma unroll
        for (int e = 0; e < 8; ++e) {
            float ex = __expf((float)hv[i][e] - mx);
            ev[e] = __builtin_bit_cast(_Float16, f2bf_u(ex));  // bf16 bits for PV
            float a = ex * iv;                                  // full-precision att
            if (e < 4) o0[e] = a; else o1[e - 4] = a;
        }
        *(half8*)(Srow + i * 64) = ev;
        *(floatx4*)(arow + i * 64)     = o0;   // plain stores: L2 merges lines
        *(floatx4*)(arow + i * 64 + 4) = o1;
    }
    __syncthreads();   // e-bits + rowinv visible to all before PV

    // ---- Phase 3: out = (e @ V) * inv_l. Each wave owns 32 of 128 d-cols ----
    // 4-slot rings, distance 3, on V (global) and P (LDS).
    const _Float16* sp0 = S + (size_t)l15 * SSTRIDE + quad * 8;
    const _Float16* sp1 = S + (size_t)(16 + l15) * SSTRIDE + quad * 8;

    short8 pr0[4], pr1[4];
    #pragma unroll
    for (int p = 0; p < 3; ++p) {
        pr0[p] = __builtin_bit_cast(short8, *(const half8*)(sp0 + p * 32));
        pr1[p] = __builtin_bit_cast(short8, *(const half8*)(sp1 + p * 32));
    }

    floatx4 o00 = {0.f,0.f,0.f,0.f}, o01 = o00, o10 = o00, o11 = o00;
    #pragma unroll
    for (int ks = 0; ks < 32; ++ks) {
        if (ks + 3 < 32) {                   // compile-time guard (unrolled)
            const int pf = ks + 3, sp = pf & 3;
            vr0[sp] = *(const short8*)(vrow0 + pf * 32);
            vr1[sp] = *(const short8*)(vrow1 + pf * 32);
            pr0[sp] = __builtin_bit_cast(short8, *(const half8*)(sp0 + pf * 32));
            pr1[sp] = __builtin_bit_cast(short8, *(const half8*)(sp1 + pf * 32));
        }
        const int sl = ks & 3;
        o00 = __builtin_amdgcn_mfma_f32_16x16x32_bf16(pr0[sl], vr0[sl], o00, 0, 0, 0);
        o01 = __builtin_amdgcn_mfma_f32_16x16x32_bf16(pr0[sl], vr1[sl], o01, 0, 0, 0);
        o10 = __builtin_amdgcn_mfma_f32_16x16x32_bf16(pr1[sl], vr0[sl], o10, 0, 0, 0);
        o11 = __builtin_amdgcn_mfma_f32_16x16x32_bf16(pr1[sl], vr1[sl], o11, 0, 0, 0);
    }

    #pragma unroll
    for (int ct = 0; ct < 2; ++ct) {
        int col = c0p + ct * 16 + l15;     // d index 0..127
        float agg = 0.f;
        #pragma unroll
        for (int rt = 0; rt < 2; ++rt) {
            floatx4 oo = (rt == 0) ? (ct == 0 ? o00 : o01) : (ct == 0 ? o10 : o11);
            #pragma unroll
            for (int r = 0; r < 4; ++r) {
                int rw = rt * 16 + quad * 4 + r;
                float val = oo[r] * rowinv[rw];
                out[((size_t)(n * TT + t0 + rw)) * (HH * DD) + h * DD + col] = val;
                agg += val;
            }
        }
        atomicAdd(outagg + n * (HH * DD) + h * DD + col, agg * (1.f / (float)TT));
    }
}

extern "C" void kernel_launch(void* const* d_in, const int* in_sizes, int n_in,
                              void* d_out, int out_size, void* d_ws, size_t ws_size,
                              hipStream_t stream) {
    const float* x    = (const float*)d_in[0];
    const int*   mask = (const int*)d_in[1];      // bool -> int32 (verified)
    const float* wts  = (const float*)d_in[2];
    const float* Wq = (const float*)d_in[3];
    const float* bq = (const float*)d_in[4];
    const float* Wk = (const float*)d_in[5];
    const float* bk = (const float*)d_in[6];
    const float* Wv = (const float*)d_in[7];
    const float* bv = (const float*)d_in[8];

    float* out    = (float*)d_out;                                  // [8,1024,1024]
    float* outagg = out + (size_t)NB * TT * HH * DD;                // [8,1024]
    float* att    = outagg + NB * HH * DD;                          // [8,8,1024,1024]

    unsigned short* qb = (unsigned short*)d_ws;                     // 16.78 MB each
    unsigned short* kb = qb + (size_t)NB * HH * TT * DD;
    unsigned short* vt = kb + (size_t)NB * HH * TT * DD;

    hipMemsetAsync(outagg, 0, (size_t)NB * HH * DD * sizeof(float), stream);
    proj_kernel<<<3072, 256, 0, stream>>>(x, Wq, bq, Wk, bk, Wv, bv, qb, kb, vt);
    attn_kernel<<<2048, 256, 32 * SSTRIDE * 2 + 128, stream>>>(
        qb, kb, vt, wts, mask, out, outagg, att);
}

// Round 4
// 747.276 us; speedup vs baseline: 1.1625x; 1.0546x over previous
//
#include <hip/hip_runtime.h>
#include <hip/hip_bf16.h>
#include <hip/hip_fp16.h>

// Problem constants (TempoAttention: N=8, T=1024, D=128, H=8)
#define NB 8
#define TT 1024
#define DD 128
#define HH 8

using short8  = __attribute__((ext_vector_type(8))) short;    // 8 bf16 (4 VGPRs)
using floatx4 = __attribute__((ext_vector_type(4))) float;    // MFMA C/D
using half8   = __attribute__((ext_vector_type(8))) _Float16;
using half4   = __attribute__((ext_vector_type(4))) _Float16; // packed b64 LDS store
using intx4   = __attribute__((ext_vector_type(4))) int;

// fp32 -> bf16 (RNE)
__device__ __forceinline__ unsigned short f2bf_u(float f) {
    union { float f; unsigned u; } v; v.f = f;
    return (unsigned short)((v.u + 0x7fffu + ((v.u >> 16) & 1u)) >> 16);
}

// ---------------------------------------------------------------------------
// Projection kernel: q = x@Wq^T+bq etc. -> bf16 in MFMA-friendly layouts.
//   q,k : [n,h,t,d]  (row = token, contiguous d)
//   v   : [n,h,d,t]  (transposed so PV B-fragments are contiguous along t)
// GEMM M=8192 (n,t), N=1024 (h*d), K=128. block = 4 waves x 16 rows, 128 cols.
// VERIFIED — do not touch.
// ---------------------------------------------------------------------------
__global__ __launch_bounds__(256, 2) void proj_kernel(
    const float* __restrict__ x,
    const float* __restrict__ Wq, const float* __restrict__ bq,
    const float* __restrict__ Wk, const float* __restrict__ bk,
    const float* __restrict__ Wv, const float* __restrict__ bv,
    unsigned short* __restrict__ qb, unsigned short* __restrict__ kb,
    unsigned short* __restrict__ vt)
{
    int b     = blockIdx.x;
    int which = b >> 10;          // 0=q 1=k 2=v
    int rem   = b & 1023;
    int mblk  = rem >> 3;         // 0..127 (64 rows each)
    int nblk  = rem & 7;          // 0..7   (128 cols each)
    int tid   = threadIdx.x;
    int wid   = tid >> 6, lane = tid & 63;
    int l15   = lane & 15, quad = lane >> 4;
    int m0    = mblk * 64 + wid * 16;

    const float* W    = (which == 0) ? Wq : (which == 1) ? Wk : Wv;
    const float* bias = (which == 0) ? bq : (which == 1) ? bk : bv;
    unsigned short* dst = (which == 0) ? qb : (which == 1) ? kb : vt;

    // A fragments: x rows (fp32 -> bf16), A[m=l15][k=quad*8+j]
    short8 a[4];
    const float* xr = x + (size_t)(m0 + l15) * DD + quad * 8;
    #pragma unroll
    for (int kk = 0; kk < 4; ++kk) {
        const float* p = xr + kk * 32;
        short8 t;
        #pragma unroll
        for (int j = 0; j < 8; ++j) t[j] = (short)f2bf_u(p[j]);
        a[kk] = t;
    }

    floatx4 acc[8];
    #pragma unroll
    for (int ct = 0; ct < 8; ++ct) acc[ct] = (floatx4){0.f, 0.f, 0.f, 0.f};

    for (int ct = 0; ct < 8; ++ct) {
        int c = nblk * 128 + ct * 16 + l15;          // output channel (B n-index)
        const float* wr = W + (size_t)c * DD + quad * 8;
        #pragma unroll
        for (int kk = 0; kk < 4; ++kk) {
            const float* p = wr + kk * 32;
            short8 bf;
            #pragma unroll
            for (int j = 0; j < 8; ++j) bf[j] = (short)f2bf_u(p[j]);
            acc[ct] = __builtin_amdgcn_mfma_f32_16x16x32_bf16(a[kk], bf, acc[ct], 0, 0, 0);
        }
    }

    // Epilogue: C/D layout col=l15, row=quad*4+r
    #pragma unroll
    for (int ct = 0; ct < 8; ++ct) {
        int c  = nblk * 128 + ct * 16 + l15;
        int h  = c >> 7, dd = c & 127;
        float bsv = bias[c];
        #pragma unroll
        for (int r = 0; r < 4; ++r) {
            int m = m0 + quad * 4 + r;
            int n = m >> 10, t = m & 1023;
            unsigned short v = f2bf_u(acc[ct][r] + bsv);
            size_t idx;
            if (which == 2) idx = ((size_t)(n * HH + h) * DD + dd) * TT + t;   // v^T
            else            idx = ((size_t)(n * HH + h) * TT + t) * DD + dd;   // q,k
            dst[idx] = v;
        }
    }
}

// ---------------------------------------------------------------------------
// Fused attention kernel. One block = (n,h) x 32 query rows. 256 threads.
//
// R4: base = R1 structure (best measured, 288us: rotate-d2 wts pipeline,
// d1 K, reg-cached softmax, NT att/out stores). R3's deeper rings REGRESSED
// (333us, FETCH+36MB, WRITE+70MB) -> more per-wave MLP is not the lever.
// New mechanism this round: CACHE DISCIPLINE. Per XCD the K/V working set of
// its 8 co-resident (n,h) groups is exactly 4MB = L2 size, but the single-use
// wts read stream (32MB/XCD) cycles L2 every ~20us and flushes K/V to
// L3-latency. Nontemporal LOADS on wts keep L2 for K/V/Q (tight temporal
// reuse: all 32 blocks of a group are co-resident) -> K/V at L2 latency.
// NT stores on att/out retained from R1 (keeps the 32MB/XCD att write stream
// from allocating L2; measured cost ~+60MB WRITE amplification).
// Phase 3: depth-2 ping-pong on V/P (static indices), V prefilled during
// phase-2 stores.
// Math identical to verified R1: swapped QK^T mfma(K,Q), -65504 sentinel,
// same fp16/bf16 path.
// ---------------------------------------------------------------------------
#define SSTRIDE 1032  // halves; +8 pad breaks power-of-2 bank aliasing

__global__ __launch_bounds__(256, 2) void attn_kernel(
    const unsigned short* __restrict__ qb, const unsigned short* __restrict__ kb,
    const unsigned short* __restrict__ vt,
    const float* __restrict__ wts, const int* __restrict__ mask,
    float* __restrict__ out, float* __restrict__ outagg, float* __restrict__ att)
{
    extern __shared__ char smem[];
    _Float16* S   = (_Float16*)smem;
    float* rowinv = (float*)(smem + 32 * SSTRIDE * 2);

    // XCD swizzle: all 32 tiles of one (n,h) group land on one XCD (b%8)
    int b    = blockIdx.x;
    int slot = b & 7, j = b >> 3;
    int tile = j & 31, gq = j >> 5;
    int g    = gq * 8 + slot;          // n*H + h, 0..63
    int n    = g >> 3, h = g & 7;
    int t0   = tile * 32;

    int tid = threadIdx.x;
    int wid = tid >> 6, lane = tid & 63;
    int l15 = lane & 15, quad = lane >> 4;

    const unsigned short* qp = qb + ((size_t)g * TT + t0) * DD;
    const unsigned short* kp = kb + (size_t)g * TT * DD;
    const unsigned short* vp = vt + (size_t)g * DD * TT;
    const float* wp = wts + (size_t)g * TT * TT + (size_t)t0 * TT;
    const int*   mp = mask + n * TT;
    float* attp = att + (size_t)g * TT * TT + (size_t)t0 * TT;

    // ---- Phase 1: S = mask(weights * scale * (Q K^T)) ----
    // Swapped MFMA (verified): mfma(K,Q) -> D col=l15=query, row=quad*4+r=key,
    // so per-lane w/mask are 4 CONSECUTIVE keys -> float4/int4 loads.
    short8 aq[2][4];
    #pragma unroll
    for (int rt = 0; rt < 2; ++rt)
        #pragma unroll
        for (int kk = 0; kk < 4; ++kk)
            aq[rt][kk] = *(const short8*)(qp + (size_t)(rt * 16 + l15) * DD + kk * 32 + quad * 8);

    const int c0 = wid * 256;                 // each wave owns a 256-key strip
    const float scale = 0.08838834764831845f; // 1/sqrt(128)

    const float* wrow0 = wp + (size_t)l15 * TT + c0 + quad * 4;  // w[query=l15][key..]
    const float* wrow1 = wrow0 + (size_t)16 * TT;                // queries +16
    const unsigned short* kcol = kp + (size_t)(c0 + l15) * DD + quad * 8;
    const int* mrow = mp + c0 + quad * 4;
    _Float16* sst0 = S + (size_t)l15 * SSTRIDE + c0 + quad * 4;
    _Float16* sst1 = sst0 + (size_t)16 * SSTRIDE;

    // Software pipeline (R1 depths): wts 2 tiles ahead (NT: bypass L2), K 1.
    floatx4 w0_c, w1_c, w0_n, w1_n;
    intx4   mk_c, mk_n;
    short8  kf[4];

    w0_c = __builtin_nontemporal_load((const floatx4*)(wrow0));
    w1_c = __builtin_nontemporal_load((const floatx4*)(wrow1));
    mk_c = *(const intx4*)(mrow);
    w0_n = __builtin_nontemporal_load((const floatx4*)(wrow0 + 16));
    w1_n = __builtin_nontemporal_load((const floatx4*)(wrow1 + 16));
    mk_n = *(const intx4*)(mrow + 16);
    #pragma unroll
    for (int kk = 0; kk < 4; ++kk)
        kf[kk] = *(const short8*)(kcol + kk * 32);

    for (int ct = 0; ct < 16; ++ct) {
        // Prefetch (clamped addresses, branch-free).
        int ctk = (ct + 1 < 16) ? ct + 1 : 15;   // K tile ct+1
        int ctw = (ct + 2 < 16) ? ct + 2 : 15;   // w/mask tile ct+2
        short8 kn[4];
        #pragma unroll
        for (int kk = 0; kk < 4; ++kk)
            kn[kk] = *(const short8*)(kcol + ctk * 16 * DD + kk * 32);
        floatx4 nw0 = __builtin_nontemporal_load((const floatx4*)(wrow0 + ctw * 16));
        floatx4 nw1 = __builtin_nontemporal_load((const floatx4*)(wrow1 + ctw * 16));
        intx4   nmk = *(const intx4*)(mrow + ctw * 16);

        // Swapped MFMA: D[m=key][n=query] -> col=l15=query, row=quad*4+r=key.
        floatx4 acc0 = {0.f,0.f,0.f,0.f}, acc1 = {0.f,0.f,0.f,0.f};
        #pragma unroll
        for (int kk = 0; kk < 4; ++kk) {
            acc0 = __builtin_amdgcn_mfma_f32_16x16x32_bf16(kf[kk], aq[0][kk], acc0, 0, 0, 0);
            acc1 = __builtin_amdgcn_mfma_f32_16x16x32_bf16(kf[kk], aq[1][kk], acc1, 0, 0, 0);
        }

        // Epilogue: 4 consecutive keys per lane -> packed b64 LDS store.
        half4 h0, h1;
        #pragma unroll
        for (int r = 0; r < 4; ++r) {
            h0[r] = (_Float16)(mk_c[r] ? -65504.f : acc0[r] * scale * w0_c[r]);
            h1[r] = (_Float16)(mk_c[r] ? -65504.f : acc1[r] * scale * w1_c[r]);
        }
        *(half4*)(sst0 + ct * 16) = h0;
        *(half4*)(sst1 + ct * 16) = h1;

        // Rotate pipeline registers.
        #pragma unroll
        for (int kk = 0; kk < 4; ++kk) kf[kk] = kn[kk];
        w0_c = w0_n; w1_c = w1_n; mk_c = mk_n;
        w0_n = nw0;  w1_n = nw1;  mk_n = nmk;
    }
    __syncthreads();

    // ---- Phase 2: softmax. 8 lanes per row (same wave) -> shfl reductions.
    // Score row cached in regs (single LDS pass), 8-way ILP chains.
    int row = tid >> 3;          // 0..31
    int jj  = tid & 7;           // 0..7, owns cols {jj*8 + i*64 + e}
    _Float16* Srow = S + row * SSTRIDE + jj * 8;

    half8 hv[16];
    #pragma unroll
    for (int i = 0; i < 16; ++i) hv[i] = *(const half8*)(Srow + i * 64);

    float m8[8];
    #pragma unroll
    for (int e = 0; e < 8; ++e) m8[e] = (float)hv[0][e];
    #pragma unroll
    for (int i = 1; i < 16; ++i)
        #pragma unroll
        for (int e = 0; e < 8; ++e) m8[e] = fmaxf(m8[e], (float)hv[i][e]);
    float mx = fmaxf(fmaxf(fmaxf(m8[0], m8[1]), fmaxf(m8[2], m8[3])),
                     fmaxf(fmaxf(m8[4], m8[5]), fmaxf(m8[6], m8[7])));
    mx = fmaxf(mx, __shfl_xor(mx, 1));
    mx = fmaxf(mx, __shfl_xor(mx, 2));
    mx = fmaxf(mx, __shfl_xor(mx, 4));

    float s8[8] = {0.f,0.f,0.f,0.f,0.f,0.f,0.f,0.f};
    #pragma unroll
    for (int i = 0; i < 16; ++i)
        #pragma unroll
        for (int e = 0; e < 8; ++e) s8[e] += __expf((float)hv[i][e] - mx);
    float sum = ((s8[0] + s8[1]) + (s8[2] + s8[3])) + ((s8[4] + s8[5]) + (s8[6] + s8[7]));
    sum += __shfl_xor(sum, 1);
    sum += __shfl_xor(sum, 2);
    sum += __shfl_xor(sum, 4);
    float iv = 1.f / sum;              // all 8 lanes of the row group have it
    if (jj == 0) rowinv[row] = iv;     // PV epilogue needs it per C-row

    // Prefill phase-3 V ping-pong NOW (independent of S) — latency hides
    // under the exp/store loop below.
    int c0p = wid * 32;
    const unsigned short* vrow0 = vp + (size_t)(c0p + l15) * TT + quad * 8;
    const unsigned short* vrow1 = vp + (size_t)(c0p + 16 + l15) * TT + quad * 8;
    short8 vb0[2], vb1[2];
    #pragma unroll
    for (int p = 0; p < 2; ++p) {
        vb0[p] = *(const short8*)(vrow0 + p * 32);
        vb1[p] = *(const short8*)(vrow1 + p * 32);
    }

    float* arow = attp + (size_t)row * TT + jj * 8;
    #pragma unroll
    for (int i = 0; i < 16; ++i) {
        half8 ev;
        floatx4 o0, o1;
        #pragma unroll
        for (int e = 0; e < 8; ++e) {
            float ex = __expf((float)hv[i][e] - mx);
            ev[e] = __builtin_bit_cast(_Float16, f2bf_u(ex));  // bf16 bits for PV
            float a = ex * iv;                                  // full-precision att
            if (e < 4) o0[e] = a; else o1[e - 4] = a;
        }
        *(half8*)(Srow + i * 64) = ev;
        __builtin_nontemporal_store(o0, (floatx4*)(arow + i * 64));
        __builtin_nontemporal_store(o1, (floatx4*)(arow + i * 64 + 4));
    }
    __syncthreads();   // e-bits + rowinv visible to all before PV

    // ---- Phase 3: out = (e @ V) * inv_l. Each wave owns 32 of 128 d-cols ----
    // Depth-2 ping-pong on V (global, L2-resident now) and P (LDS),
    // all indices compile-time static.
    const _Float16* sp0 = S + (size_t)l15 * SSTRIDE + quad * 8;
    const _Float16* sp1 = S + (size_t)(16 + l15) * SSTRIDE + quad * 8;

    short8 pa0[2], pa1[2];
    #pragma unroll
    for (int p = 0; p < 2; ++p) {
        pa0[p] = __builtin_bit_cast(short8, *(const half8*)(sp0 + p * 32));
        pa1[p] = __builtin_bit_cast(short8, *(const half8*)(sp1 + p * 32));
    }

    floatx4 o00 = {0.f,0.f,0.f,0.f}, o01 = o00, o10 = o00, o11 = o00;
    #pragma unroll
    for (int ks = 0; ks < 32; ++ks) {
        const int sl = ks & 1;
        short8 a0 = pa0[sl], a1 = pa1[sl], b0 = vb0[sl], b1 = vb1[sl];
        if (ks + 2 < 32) {                   // compile-time guard (unrolled)
            vb0[sl] = *(const short8*)(vrow0 + (ks + 2) * 32);
            vb1[sl] = *(const short8*)(vrow1 + (ks + 2) * 32);
            pa0[sl] = __builtin_bit_cast(short8, *(const half8*)(sp0 + (ks + 2) * 32));
            pa1[sl] = __builtin_bit_cast(short8, *(const half8*)(sp1 + (ks + 2) * 32));
        }
        o00 = __builtin_amdgcn_mfma_f32_16x16x32_bf16(a0, b0, o00, 0, 0, 0);
        o01 = __builtin_amdgcn_mfma_f32_16x16x32_bf16(a0, b1, o01, 0, 0, 0);
        o10 = __builtin_amdgcn_mfma_f32_16x16x32_bf16(a1, b0, o10, 0, 0, 0);
        o11 = __builtin_amdgcn_mfma_f32_16x16x32_bf16(a1, b1, o11, 0, 0, 0);
    }

    #pragma unroll
    for (int ct = 0; ct < 2; ++ct) {
        int col = c0p + ct * 16 + l15;     // d index 0..127
        float agg = 0.f;
        #pragma unroll
        for (int rt = 0; rt < 2; ++rt) {
            floatx4 oo = (rt == 0) ? (ct == 0 ? o00 : o01) : (ct == 0 ? o10 : o11);
            #pragma unroll
            for (int r = 0; r < 4; ++r) {
                int rw = rt * 16 + quad * 4 + r;
                float val = oo[r] * rowinv[rw];
                __builtin_nontemporal_store(
                    val, &out[((size_t)(n * TT + t0 + rw)) * (HH * DD) + h * DD + col]);
                agg += val;
            }
        }
        atomicAdd(outagg + n * (HH * DD) + h * DD + col, agg * (1.f / (float)TT));
    }
}

extern "C" void kernel_launch(void* const* d_in, const int* in_sizes, int n_in,
                              void* d_out, int out_size, void* d_ws, size_t ws_size,
                              hipStream_t stream) {
    const float* x    = (const float*)d_in[0];
    const int*   mask = (const int*)d_in[1];      // bool -> int32 (verified)
    const float* wts  = (const float*)d_in[2];
    const float* Wq = (const float*)d_in[3];
    const float* bq = (const float*)d_in[4];
    const float* Wk = (const float*)d_in[5];
    const float* bk = (const float*)d_in[6];
    const float* Wv = (const float*)d_in[7];
    const float* bv = (const float*)d_in[8];

    float* out    = (float*)d_out;                                  // [8,1024,1024]
    float* outagg = out + (size_t)NB * TT * HH * DD;                // [8,1024]
    float* att    = outagg + NB * HH * DD;                          // [8,8,1024,1024]

    unsigned short* qb = (unsigned short*)d_ws;                     // 16.78 MB each
    unsigned short* kb = qb + (size_t)NB * HH * TT * DD;
    unsigned short* vt = kb + (size_t)NB * HH * TT * DD;

    hipMemsetAsync(outagg, 0, (size_t)NB * HH * DD * sizeof(float), stream);
    proj_kernel<<<3072, 256, 0, stream>>>(x, Wq, bq, Wk, bk, Wv, bv, qb, kb, vt);
    attn_kernel<<<2048, 256, 32 * SSTRIDE * 2 + 128, stream>>>(
        qb, kb, vt, wts, mask, out, outagg, att);
}

// Round 6
// 741.646 us; speedup vs baseline: 1.1713x; 1.0076x over previous
//
#include <hip/hip_runtime.h>
#include <hip/hip_bf16.h>
#include <hip/hip_fp16.h>

// Problem constants (TempoAttention: N=8, T=1024, D=128, H=8)
#define NB 8
#define TT 1024
#define DD 128
#define HH 8

using short8  = __attribute__((ext_vector_type(8))) short;    // 8 bf16 (4 VGPRs)
using floatx4 = __attribute__((ext_vector_type(4))) float;    // MFMA C/D
using half8   = __attribute__((ext_vector_type(8))) _Float16;
using half4   = __attribute__((ext_vector_type(4))) _Float16; // packed b64 LDS store
using intx4   = __attribute__((ext_vector_type(4))) int;

// fp32 -> bf16 (RNE)
__device__ __forceinline__ unsigned short f2bf_u(float f) {
    union { float f; unsigned u; } v; v.f = f;
    return (unsigned short)((v.u + 0x7fffu + ((v.u >> 16) & 1u)) >> 16);
}

// ---------------------------------------------------------------------------
// Projection kernel: q = x@Wq^T+bq etc. -> bf16 in MFMA-friendly layouts.
//   q,k : [n,h,t,d]  (row = token, contiguous d)
//   v   : [n,h,d,t]  (transposed so PV B-fragments are contiguous along t)
// GEMM M=8192 (n,t), N=1024 (h*d), K=128. block = 4 waves x 16 rows, 128 cols.
// VERIFIED — do not touch.
// ---------------------------------------------------------------------------
__global__ __launch_bounds__(256, 2) void proj_kernel(
    const float* __restrict__ x,
    const float* __restrict__ Wq, const float* __restrict__ bq,
    const float* __restrict__ Wk, const float* __restrict__ bk,
    const float* __restrict__ Wv, const float* __restrict__ bv,
    unsigned short* __restrict__ qb, unsigned short* __restrict__ kb,
    unsigned short* __restrict__ vt)
{
    int b     = blockIdx.x;
    int which = b >> 10;          // 0=q 1=k 2=v
    int rem   = b & 1023;
    int mblk  = rem >> 3;         // 0..127 (64 rows each)
    int nblk  = rem & 7;          // 0..7   (128 cols each)
    int tid   = threadIdx.x;
    int wid   = tid >> 6, lane = tid & 63;
    int l15   = lane & 15, quad = lane >> 4;
    int m0    = mblk * 64 + wid * 16;

    const float* W    = (which == 0) ? Wq : (which == 1) ? Wk : Wv;
    const float* bias = (which == 0) ? bq : (which == 1) ? bk : bv;
    unsigned short* dst = (which == 0) ? qb : (which == 1) ? kb : vt;

    // A fragments: x rows (fp32 -> bf16), A[m=l15][k=quad*8+j]
    short8 a[4];
    const float* xr = x + (size_t)(m0 + l15) * DD + quad * 8;
    #pragma unroll
    for (int kk = 0; kk < 4; ++kk) {
        const float* p = xr + kk * 32;
        short8 t;
        #pragma unroll
        for (int j = 0; j < 8; ++j) t[j] = (short)f2bf_u(p[j]);
        a[kk] = t;
    }

    floatx4 acc[8];
    #pragma unroll
    for (int ct = 0; ct < 8; ++ct) acc[ct] = (floatx4){0.f, 0.f, 0.f, 0.f};

    for (int ct = 0; ct < 8; ++ct) {
        int c = nblk * 128 + ct * 16 + l15;          // output channel (B n-index)
        const float* wr = W + (size_t)c * DD + quad * 8;
        #pragma unroll
        for (int kk = 0; kk < 4; ++kk) {
            const float* p = wr + kk * 32;
            short8 bf;
            #pragma unroll
            for (int j = 0; j < 8; ++j) bf[j] = (short)f2bf_u(p[j]);
            acc[ct] = __builtin_amdgcn_mfma_f32_16x16x32_bf16(a[kk], bf, acc[ct], 0, 0, 0);
        }
    }

    // Epilogue: C/D layout col=l15, row=quad*4+r
    #pragma unroll
    for (int ct = 0; ct < 8; ++ct) {
        int c  = nblk * 128 + ct * 16 + l15;
        int h  = c >> 7, dd = c & 127;
        float bsv = bias[c];
        #pragma unroll
        for (int r = 0; r < 4; ++r) {
            int m = m0 + quad * 4 + r;
            int n = m >> 10, t = m & 1023;
            unsigned short v = f2bf_u(acc[ct][r] + bsv);
            size_t idx;
            if (which == 2) idx = ((size_t)(n * HH + h) * DD + dd) * TT + t;   // v^T
            else            idx = ((size_t)(n * HH + h) * TT + t) * DD + dd;   // q,k
            dst[idx] = v;
        }
    }
}

// ---------------------------------------------------------------------------
// Fused attention kernel. One block = (n,h) x 32 query rows. 256 threads.
//
// R5 (resubmitted R6 — previous round failed in the container broker, kernel
// never ran): DECOUPLE the wts stream from the MFMA loop. R4 (267us, 2.3TB/s)
// still consumed w inside the serial QK^T loop: iteration ct needs w(ct)
// loaded d=2 iters (~200cy) earlier vs ~900cy NT latency -> ~700cy exposed
// per iter, and vmcnt's in-order retirement makes the fast K loads wait
// behind slow wts.
// Now: phase 1 = pure QK^T (K from L2 only), stores RAW fp16(acc*scale) in S.
// Phase 2 pass A applies w*mask: each thread owns 8 CONTIGUOUS cols per chunk
// -> w is a flat 2x dwordx4 NT stream, 4-slot ring, no compute dependency ->
// runs at BW share. Cost: one extra fp16 rounding of the score (absmax
// ~0.006->~0.007 expected).
// Phase 3 + proj + NT-store discipline unchanged from R4 (verified).
// ---------------------------------------------------------------------------
#define SSTRIDE 1032  // halves; +8 pad breaks power-of-2 bank aliasing

__global__ __launch_bounds__(256, 2) void attn_kernel(
    const unsigned short* __restrict__ qb, const unsigned short* __restrict__ kb,
    const unsigned short* __restrict__ vt,
    const float* __restrict__ wts, const int* __restrict__ mask,
    float* __restrict__ out, float* __restrict__ outagg, float* __restrict__ att)
{
    extern __shared__ char smem[];
    _Float16* S   = (_Float16*)smem;
    float* rowinv = (float*)(smem + 32 * SSTRIDE * 2);

    // XCD swizzle: all 32 tiles of one (n,h) group land on one XCD (b%8)
    int b    = blockIdx.x;
    int slot = b & 7, j = b >> 3;
    int tile = j & 31, gq = j >> 5;
    int g    = gq * 8 + slot;          // n*H + h, 0..63
    int n    = g >> 3, h = g & 7;
    int t0   = tile * 32;

    int tid = threadIdx.x;
    int wid = tid >> 6, lane = tid & 63;
    int l15 = lane & 15, quad = lane >> 4;

    const unsigned short* qp = qb + ((size_t)g * TT + t0) * DD;
    const unsigned short* kp = kb + (size_t)g * TT * DD;
    const unsigned short* vp = vt + (size_t)g * DD * TT;
    const float* wp = wts + (size_t)g * TT * TT + (size_t)t0 * TT;
    const int*   mp = mask + n * TT;
    float* attp = att + (size_t)g * TT * TT + (size_t)t0 * TT;

    // ---- Phase 1: S_raw = fp16(scale * (Q K^T)) — NO wts/mask here ----
    // Swapped MFMA (verified): mfma(K,Q) -> D col=l15=query, row=quad*4+r=key.
    short8 aq[2][4];
    #pragma unroll
    for (int rt = 0; rt < 2; ++rt)
        #pragma unroll
        for (int kk = 0; kk < 4; ++kk)
            aq[rt][kk] = *(const short8*)(qp + (size_t)(rt * 16 + l15) * DD + kk * 32 + quad * 8);

    const int c0 = wid * 256;                 // each wave owns a 256-key strip
    const float scale = 0.08838834764831845f; // 1/sqrt(128)

    const unsigned short* kcol = kp + (size_t)(c0 + l15) * DD + quad * 8;
    _Float16* sst0 = S + (size_t)l15 * SSTRIDE + c0 + quad * 4;
    _Float16* sst1 = sst0 + (size_t)16 * SSTRIDE;

    short8 kf[4];
    #pragma unroll
    for (int kk = 0; kk < 4; ++kk)
        kf[kk] = *(const short8*)(kcol + kk * 32);

    for (int ct = 0; ct < 16; ++ct) {
        int ctk = (ct + 1 < 16) ? ct + 1 : 15;   // K tile ct+1 (clamped)
        short8 kn[4];
        #pragma unroll
        for (int kk = 0; kk < 4; ++kk)
            kn[kk] = *(const short8*)(kcol + ctk * 16 * DD + kk * 32);

        floatx4 acc0 = {0.f,0.f,0.f,0.f}, acc1 = {0.f,0.f,0.f,0.f};
        #pragma unroll
        for (int kk = 0; kk < 4; ++kk) {
            acc0 = __builtin_amdgcn_mfma_f32_16x16x32_bf16(kf[kk], aq[0][kk], acc0, 0, 0, 0);
            acc1 = __builtin_amdgcn_mfma_f32_16x16x32_bf16(kf[kk], aq[1][kk], acc1, 0, 0, 0);
        }

        half4 h0, h1;
        #pragma unroll
        for (int r = 0; r < 4; ++r) {
            h0[r] = (_Float16)(acc0[r] * scale);
            h1[r] = (_Float16)(acc1[r] * scale);
        }
        *(half4*)(sst0 + ct * 16) = h0;
        *(half4*)(sst1 + ct * 16) = h1;

        #pragma unroll
        for (int kk = 0; kk < 4; ++kk) kf[kk] = kn[kk];
    }
    __syncthreads();

    // ---- Phase 2: p = mask(w * S_raw); softmax; att + e-bits stores ----
    // 8 lanes per row; each lane owns cols {jj*8 + i*64 .. +7} — CONTIGUOUS,
    // so w is a pure NT stream: 2x dwordx4 per chunk, 4-slot ring (d4).
    int row = tid >> 3;          // 0..31
    int jj  = tid & 7;           // 0..7
    _Float16* Srow = S + row * SSTRIDE + jj * 8;
    const float* w2 = wp + (size_t)row * TT + jj * 8;
    const int*   m2 = mp + jj * 8;

    // Raw scores: single LDS pass into regs (lgkmcnt independent of vmcnt).
    half8 hv[16];
    #pragma unroll
    for (int i = 0; i < 16; ++i) hv[i] = *(const half8*)(Srow + i * 64);

    // 4-slot ring on w (NT) + mask (cached; L2-hot, reused by 256 blocks).
    floatx4 wA[4][2]; intx4 mkA[4][2];
    #pragma unroll
    for (int p = 0; p < 4; ++p) {
        wA[p][0]  = __builtin_nontemporal_load((const floatx4*)(w2 + p * 64));
        wA[p][1]  = __builtin_nontemporal_load((const floatx4*)(w2 + p * 64 + 4));
        mkA[p][0] = *(const intx4*)(m2 + p * 64);
        mkA[p][1] = *(const intx4*)(m2 + p * 64 + 4);
    }

    float m8[8];
    #pragma unroll
    for (int e = 0; e < 8; ++e) m8[e] = -3.0e38f;

    #pragma unroll
    for (int i = 0; i < 16; ++i) {
        const int sl = i & 3;
        floatx4 wa = wA[sl][0], wb = wA[sl][1];
        intx4   ma = mkA[sl][0], mb = mkA[sl][1];
        if (i + 4 < 16) {                    // compile-time guard (unrolled)
            wA[sl][0]  = __builtin_nontemporal_load((const floatx4*)(w2 + (i + 4) * 64));
            wA[sl][1]  = __builtin_nontemporal_load((const floatx4*)(w2 + (i + 4) * 64 + 4));
            mkA[sl][0] = *(const intx4*)(m2 + (i + 4) * 64);
            mkA[sl][1] = *(const intx4*)(m2 + (i + 4) * 64 + 4);
        }
        half8 hvi = hv[i];
        half8 pv;
        #pragma unroll
        for (int e = 0; e < 8; ++e) {
            float w  = (e < 4) ? wa[e] : wb[e - 4];
            int   mk = (e < 4) ? ma[e] : mb[e - 4];
            float p  = mk ? -65504.f : (float)hvi[e] * w;
            pv[e] = (_Float16)p;
            m8[e] = fmaxf(m8[e], p);
        }
        hv[i] = pv;
    }

    float mx = fmaxf(fmaxf(fmaxf(m8[0], m8[1]), fmaxf(m8[2], m8[3])),
                     fmaxf(fmaxf(m8[4], m8[5]), fmaxf(m8[6], m8[7])));
    mx = fmaxf(mx, __shfl_xor(mx, 1));
    mx = fmaxf(mx, __shfl_xor(mx, 2));
    mx = fmaxf(mx, __shfl_xor(mx, 4));

    float s8[8] = {0.f,0.f,0.f,0.f,0.f,0.f,0.f,0.f};
    #pragma unroll
    for (int i = 0; i < 16; ++i)
        #pragma unroll
        for (int e = 0; e < 8; ++e) s8[e] += __expf((float)hv[i][e] - mx);
    float sum = ((s8[0] + s8[1]) + (s8[2] + s8[3])) + ((s8[4] + s8[5]) + (s8[6] + s8[7]));
    sum += __shfl_xor(sum, 1);
    sum += __shfl_xor(sum, 2);
    sum += __shfl_xor(sum, 4);
    float iv = 1.f / sum;              // all 8 lanes of the row group have it
    if (jj == 0) rowinv[row] = iv;     // PV epilogue needs it per C-row

    // Prefill phase-3 V ping-pong NOW (independent of S) — latency hides
    // under the exp/store loop below.
    int c0p = wid * 32;
    const unsigned short* vrow0 = vp + (size_t)(c0p + l15) * TT + quad * 8;
    const unsigned short* vrow1 = vp + (size_t)(c0p + 16 + l15) * TT + quad * 8;
    short8 vb0[2], vb1[2];
    #pragma unroll
    for (int p = 0; p < 2; ++p) {
        vb0[p] = *(const short8*)(vrow0 + p * 32);
        vb1[p] = *(const short8*)(vrow1 + p * 32);
    }

    float* arow = attp + (size_t)row * TT + jj * 8;
    #pragma unroll
    for (int i = 0; i < 16; ++i) {
        half8 ev;
        floatx4 o0, o1;
        #pragma unroll
        for (int e = 0; e < 8; ++e) {
            float ex = __expf((float)hv[i][e] - mx);
            ev[e] = __builtin_bit_cast(_Float16, f2bf_u(ex));  // bf16 bits for PV
            float a = ex * iv;                                  // full-precision att
            if (e < 4) o0[e] = a; else o1[e - 4] = a;
        }
        *(half8*)(Srow + i * 64) = ev;
        __builtin_nontemporal_store(o0, (floatx4*)(arow + i * 64));
        __builtin_nontemporal_store(o1, (floatx4*)(arow + i * 64 + 4));
    }
    __syncthreads();   // e-bits + rowinv visible to all before PV

    // ---- Phase 3: out = (e @ V) * inv_l. Each wave owns 32 of 128 d-cols ----
    // Depth-2 ping-pong on V (global, L2-resident) and P (LDS). VERIFIED R4.
    const _Float16* sp0 = S + (size_t)l15 * SSTRIDE + quad * 8;
    const _Float16* sp1 = S + (size_t)(16 + l15) * SSTRIDE + quad * 8;

    short8 pa0[2], pa1[2];
    #pragma unroll
    for (int p = 0; p < 2; ++p) {
        pa0[p] = __builtin_bit_cast(short8, *(const half8*)(sp0 + p * 32));
        pa1[p] = __builtin_bit_cast(short8, *(const half8*)(sp1 + p * 32));
    }

    floatx4 o00 = {0.f,0.f,0.f,0.f}, o01 = o00, o10 = o00, o11 = o00;
    #pragma unroll
    for (int ks = 0; ks < 32; ++ks) {
        const int sl = ks & 1;
        short8 a0 = pa0[sl], a1 = pa1[sl], b0 = vb0[sl], b1 = vb1[sl];
        if (ks + 2 < 32) {                   // compile-time guard (unrolled)
            vb0[sl] = *(const short8*)(vrow0 + (ks + 2) * 32);
            vb1[sl] = *(const short8*)(vrow1 + (ks + 2) * 32);
            pa0[sl] = __builtin_bit_cast(short8, *(const half8*)(sp0 + (ks + 2) * 32));
            pa1[sl] = __builtin_bit_cast(short8, *(const half8*)(sp1 + (ks + 2) * 32));
        }
        o00 = __builtin_amdgcn_mfma_f32_16x16x32_bf16(a0, b0, o00, 0, 0, 0);
        o01 = __builtin_amdgcn_mfma_f32_16x16x32_bf16(a0, b1, o01, 0, 0, 0);
        o10 = __builtin_amdgcn_mfma_f32_16x16x32_bf16(a1, b0, o10, 0, 0, 0);
        o11 = __builtin_amdgcn_mfma_f32_16x16x32_bf16(a1, b1, o11, 0, 0, 0);
    }

    #pragma unroll
    for (int ct = 0; ct < 2; ++ct) {
        int col = c0p + ct * 16 + l15;     // d index 0..127
        float agg = 0.f;
        #pragma unroll
        for (int rt = 0; rt < 2; ++rt) {
            floatx4 oo = (rt == 0) ? (ct == 0 ? o00 : o01) : (ct == 0 ? o10 : o11);
            #pragma unroll
            for (int r = 0; r < 4; ++r) {
                int rw = rt * 16 + quad * 4 + r;
                float val = oo[r] * rowinv[rw];
                __builtin_nontemporal_store(
                    val, &out[((size_t)(n * TT + t0 + rw)) * (HH * DD) + h * DD + col]);
                agg += val;
            }
        }
        atomicAdd(outagg + n * (HH * DD) + h * DD + col, agg * (1.f / (float)TT));
    }
}

extern "C" void kernel_launch(void* const* d_in, const int* in_sizes, int n_in,
                              void* d_out, int out_size, void* d_ws, size_t ws_size,
                              hipStream_t stream) {
    const float* x    = (const float*)d_in[0];
    const int*   mask = (const int*)d_in[1];      // bool -> int32 (verified)
    const float* wts  = (const float*)d_in[2];
    const float* Wq = (const float*)d_in[3];
    const float* bq = (const float*)d_in[4];
    const float* Wk = (const float*)d_in[5];
    const float* bk = (const float*)d_in[6];
    const float* Wv = (const float*)d_in[7];
    const float* bv = (const float*)d_in[8];

    float* out    = (float*)d_out;                                  // [8,1024,1024]
    float* outagg = out + (size_t)NB * TT * HH * DD;                // [8,1024]
    float* att    = outagg + NB * HH * DD;                          // [8,8,1024,1024]

    unsigned short* qb = (unsigned short*)d_ws;                     // 16.78 MB each
    unsigned short* kb = qb + (size_t)NB * HH * TT * DD;
    unsigned short* vt = kb + (size_t)NB * HH * TT * DD;

    hipMemsetAsync(outagg, 0, (size_t)NB * HH * DD * sizeof(float), stream);
    proj_kernel<<<3072, 256, 0, stream>>>(x, Wq, bq, Wk, bk, Wv, bv, qb, kb, vt);
    attn_kernel<<<2048, 256, 32 * SSTRIDE * 2 + 128, stream>>>(
        qb, kb, vt, wts, mask, out, outagg, att);
}